// Round 1
// 355.369 us; speedup vs baseline: 1.0513x; 1.0513x over previous
//
#include <hip/hip_runtime.h>
#include <hip/hip_bf16.h>

// ---------------------------------------------------------------------------
// Deformable bottleneck. Round 8:
//   - k3 re-pipelined: double-buffered colsA (one barrier per k-point),
//     issue-early/combine-late gather (corner loads for k+1 in flight across
//     the MFMAs of k), 16-lane/px b128 corner loads (half the gather instrs).
//   prep : weight casts (w1b, w2b, wdb, wofb all bf16)
//   k1   : x -> 1x1 conv (512->128)+bn1+relu, MFMA -> out1b (NHWC bf16, d_out)
//   k2   : 3x3 offset conv (128->18), MFMA im2col -> offs (CHW f32)
//   k3   : deformable 3x3 (128->128)+bn2, im2col-in-LDS + MFMA -> out2b
//   k4   : 1x1 conv (128->512)+bn3+residual+relu, MFMA -> d_out (CHW f32)
// out1b lives in d_out's first 25.7 MB (d_out fully rewritten by k4).
// ---------------------------------------------------------------------------

typedef __attribute__((ext_vector_type(8))) short short8;  // 8 bf16 = 4 VGPR
typedef __attribute__((ext_vector_type(4))) float f32x4;

constexpr int Bn = 8;
constexpr int IC = 512;
constexpr int Cc = 128;
constexpr int Hh = 112;
constexpr int Ww = 112;
constexpr int Pp = Hh * Ww;          // 12544
constexpr float EPSf = 1e-5f;

// workspace layout (float units)
constexpr size_t OFS_OFFS  = 0;                                 // f32[8*18*12544] (7.2 MB)
constexpr size_t OFS_OUT2B = 2097152;                           // ushort[8*12544*128] (25.7 MB)
constexpr size_t OFS_W1B   = (size_t)Bn * Pp * IC / 2;          // ushort[128*512]
constexpr size_t OFS_W2B   = OFS_W1B + (size_t)Cc * IC / 2;     // ushort[512*128]
constexpr size_t OFS_WDB   = OFS_W2B + (size_t)IC * Cc / 2;     // ushort[9*128*128] (k,oc,ic)
constexpr size_t OFS_WOFB  = OFS_WDB + (size_t)9 * Cc * Cc / 2; // ushort[9*32*128]  (k,oc,ic)

__device__ __forceinline__ ushort f2bf(float f) {   // round-to-nearest-even
  uint u = __float_as_uint(f);
  return (ushort)((u + 0x7fffu + ((u >> 16) & 1u)) >> 16);
}
__device__ __forceinline__ float bfLO(uint u) {     // f32 of low bf16
  return __uint_as_float(u << 16);
}
__device__ __forceinline__ float bfHI(uint u) {     // f32 of high bf16
  return __uint_as_float(u & 0xffff0000u);
}
__device__ __forceinline__ uint cvtpk(float a, float b) {  // (a:lo, b:hi) bf16 pair
  __hip_bfloat162 h = __float22bfloat162_rn(make_float2(a, b));
  return *(uint*)&h;
}

// ---------------------------------------------------------------------------
__global__ __launch_bounds__(256) void prep_kernel(
    const float* __restrict__ w1, const float* __restrict__ w2,
    const float* __restrict__ wd, const float* __restrict__ woff,
    float* __restrict__ ws) {
  ushort* w1b  = (ushort*)(ws + OFS_W1B);
  ushort* w2b  = (ushort*)(ws + OFS_W2B);
  ushort* wdb  = (ushort*)(ws + OFS_WDB);
  ushort* wofb = (ushort*)(ws + OFS_WOFB);
  const int n1 = Cc * IC;          // w1b  (w1 already [oc][ic])
  const int n2 = IC * Cc;          // w2b  (w2 already [oc][ic])
  const int n3 = 9 * Cc * Cc;      // wdb  [k][oc][ic]
  const int n4 = 9 * 32 * Cc;      // wofb [k][oc(pad32)][ic]
  const int total = n1 + n2 + n3 + n4;
  for (int idx = blockIdx.x * blockDim.x + threadIdx.x; idx < total;
       idx += gridDim.x * blockDim.x) {
    if (idx < n1) {
      w1b[idx] = f2bf(w1[idx]);
    } else if (idx < n1 + n2) {
      int t = idx - n1;
      w2b[t] = f2bf(w2[t]);
    } else if (idx < n1 + n2 + n3) {
      int t = idx - n1 - n2;
      int k = t / (Cc * Cc), r = t % (Cc * Cc);
      int oc = r / Cc, ic = r % Cc;
      wdb[t] = f2bf(wd[(oc * Cc + ic) * 9 + k]);
    } else {
      int t = idx - n1 - n2 - n3;
      int k = t / (32 * Cc), r = t % (32 * Cc);
      int oc = r / Cc, ic = r % Cc;
      wofb[t] = (oc < 18) ? f2bf(woff[(oc * Cc + ic) * 9 + k]) : (ushort)0;
    }
  }
}

// ---------------------------------------------------------------------------
// k1: fused transpose + 1x1 conv (512->128) + bn1 + relu via MFMA.
// Reads x f32 CHW directly; stages 128-ic chunks transposed+bf16 into LDS.
__global__ __launch_bounds__(256) void k1_fused_mfma(
    const float* __restrict__ x, const ushort* __restrict__ w1b,
    const float* __restrict__ b1, const float* __restrict__ g1,
    const float* __restrict__ be1, const float* __restrict__ m1,
    const float* __restrict__ v1, ushort* __restrict__ out1b) {
  __shared__ ushort At[64][136];   // [px][ic within chunk], padded (17.4 KB)

  const int tid = threadIdx.x;
  const int lane = tid & 63;
  const int wv = tid >> 6;
  const int lr = lane & 15, lg = lane >> 4;
  const int orig = blockIdx.x;
  const int bid = (orig & 7) * 196 + (orig >> 3);   // bijective XCD chunk swizzle
  const int bi = bid / 196;
  const int p0 = (bid % 196) * 64;

  // staging role: thread handles ic pair (ic2, ic2+1), px quads (t&3)*4 + 16i
  const int ic2 = (tid >> 2) * 2;
  const int pq = (tid & 3) * 4;

  const ushort* Bw = w1b + (size_t)(wv * 32) * IC;
  const float* xbase = x + (size_t)bi * IC * Pp + p0 + pq;

  f32x4 acc[4][2];
#pragma unroll
  for (int m = 0; m < 4; ++m) { acc[m][0] = (f32x4)0.f; acc[m][1] = (f32x4)0.f; }

  float4 pv0[4], pv1[4];
  {
    const float* r0 = xbase + (size_t)ic2 * Pp;
    const float* r1 = r0 + Pp;
#pragma unroll
    for (int i = 0; i < 4; ++i) {
      pv0[i] = *(const float4*)(r0 + 16 * i);
      pv1[i] = *(const float4*)(r1 + 16 * i);
    }
  }

#pragma unroll
  for (int ch = 0; ch < 4; ++ch) {
    const int c0 = ch * 128;
    // ---- write staged regs -> At (packed bf16 pairs)
#pragma unroll
    for (int i = 0; i < 4; ++i) {
      int px = pq + 16 * i;
      *(uint*)&At[px + 0][ic2] = cvtpk(pv0[i].x, pv1[i].x);
      *(uint*)&At[px + 1][ic2] = cvtpk(pv0[i].y, pv1[i].y);
      *(uint*)&At[px + 2][ic2] = cvtpk(pv0[i].z, pv1[i].z);
      *(uint*)&At[px + 3][ic2] = cvtpk(pv0[i].w, pv1[i].w);
    }
    __syncthreads();

    // ---- prefetch next chunk (in flight during MFMA below)
    if (ch < 3) {
      const float* r0 = xbase + (size_t)(c0 + 128 + ic2) * Pp;
      const float* r1 = r0 + Pp;
#pragma unroll
      for (int i = 0; i < 4; ++i) {
        pv0[i] = *(const float4*)(r0 + 16 * i);
        pv1[i] = *(const float4*)(r1 + 16 * i);
      }
    }

    // ---- MFMA over this 128-ic chunk
#pragma unroll
    for (int ks = 0; ks < 4; ++ks) {
      short8 b0 = *(const short8*)(Bw + (size_t)lr * IC + c0 + ks * 32 + 8 * lg);
      short8 b1v = *(const short8*)(Bw + (size_t)(16 + lr) * IC + c0 + ks * 32 + 8 * lg);
#pragma unroll
      for (int m = 0; m < 4; ++m) {
        short8 a = *(const short8*)&At[m * 16 + lr][ks * 32 + 8 * lg];
        acc[m][0] = __builtin_amdgcn_mfma_f32_16x16x32_bf16(a, b0, acc[m][0], 0, 0, 0);
        acc[m][1] = __builtin_amdgcn_mfma_f32_16x16x32_bf16(a, b1v, acc[m][1], 0, 0, 0);
      }
    }
    __syncthreads();
  }

#pragma unroll
  for (int n = 0; n < 2; ++n) {
    int oc = wv * 32 + n * 16 + lr;
    float inv = g1[oc] * rsqrtf(v1[oc] + EPSf);
    float sh = (b1[oc] - m1[oc]) * inv + be1[oc];
#pragma unroll
    for (int m = 0; m < 4; ++m) {
#pragma unroll
      for (int r = 0; r < 4; ++r) {
        int p = p0 + m * 16 + lg * 4 + r;
        out1b[((size_t)bi * Pp + p) * Cc + oc] =
            f2bf(fmaxf(acc[m][n][r] * inv + sh, 0.f));
      }
    }
  }
}

// ---------------------------------------------------------------------------
// k2: offset conv (3x3, 128->18 padded 32) via MFMA im2col.
__global__ __launch_bounds__(256) void k2_offset_mfma(
    const ushort* __restrict__ out1b, const ushort* __restrict__ wofb,
    const float* __restrict__ boff, float* __restrict__ offs) {
  const int tid = threadIdx.x;
  const int lane = tid & 63;
  const int wv = tid >> 6;
  const int lr = lane & 15, lg = lane >> 4;
  const int orig = blockIdx.x;
  const int bid = (orig & 7) * 49 + (orig >> 3);
  const int bi = bid / 49;
  const int p0 = (bid % 49) * 256 + wv * 64;   // this wave's 64 px

  const ushort* src = out1b + (size_t)bi * Pp * Cc;

  int ohm[4], owm[4];
#pragma unroll
  for (int m = 0; m < 4; ++m) {
    int p = p0 + m * 16 + lr;
    ohm[m] = p / Ww;
    owm[m] = p - ohm[m] * Ww;
  }

  f32x4 acc[4][2];
#pragma unroll
  for (int m = 0; m < 4; ++m) { acc[m][0] = (f32x4)0.f; acc[m][1] = (f32x4)0.f; }

  for (int k = 0; k < 9; ++k) {
    const int kdy = k / 3 - 1, kdx = k % 3 - 1;
    const ushort* rp[4];
    bool val[4];
#pragma unroll
    for (int m = 0; m < 4; ++m) {
      int yy = ohm[m] + kdy, xx = owm[m] + kdx;
      val[m] = ((unsigned)yy < (unsigned)Hh) && ((unsigned)xx < (unsigned)Ww);
      int yc = min(max(yy, 0), Hh - 1), xc = min(max(xx, 0), Ww - 1);
      rp[m] = src + (size_t)(yc * Ww + xc) * Cc;
    }
#pragma unroll
    for (int ks = 0; ks < 4; ++ks) {
      short8 b0 = *(const short8*)(wofb + (size_t)(k * 32 + lr) * Cc + ks * 32 + 8 * lg);
      short8 b1v = *(const short8*)(wofb + (size_t)(k * 32 + 16 + lr) * Cc + ks * 32 + 8 * lg);
#pragma unroll
      for (int m = 0; m < 4; ++m) {
        short8 av = *(const short8*)(rp[m] + ks * 32 + 8 * lg);
        short8 a = val[m] ? av : (short8)0;
        acc[m][0] = __builtin_amdgcn_mfma_f32_16x16x32_bf16(a, b0, acc[m][0], 0, 0, 0);
        acc[m][1] = __builtin_amdgcn_mfma_f32_16x16x32_bf16(a, b1v, acc[m][1], 0, 0, 0);
      }
    }
  }

#pragma unroll
  for (int n = 0; n < 2; ++n) {
    int oc = n * 16 + lr;
    if (oc < 18) {
      float bo = boff[oc];
      float* orow = offs + ((size_t)bi * 18 + oc) * Pp;
#pragma unroll
      for (int m = 0; m < 4; ++m) {
        int p = p0 + m * 16 + lg * 4;
        float4 o;
        o.x = acc[m][n][0] + bo;
        o.y = acc[m][n][1] + bo;
        o.z = acc[m][n][2] + bo;
        o.w = acc[m][n][3] + bo;
        *(float4*)(orow + p) = o;
      }
    }
  }
}

// ---------------------------------------------------------------------------
// k3: deformable conv + bn2 via im2col-in-LDS + MFMA.
// Round 8: double-buffered colsA (1 barrier/k), issue-early/combine-late
// gather pipelined across the MFMAs, 16-lane/px b128 corner loads.
__global__ __launch_bounds__(256) void k3_deform_mfma(
    const ushort* __restrict__ out1b, const float* __restrict__ offs,
    const ushort* __restrict__ wdb, const float* __restrict__ bd,
    const float* __restrict__ g2, const float* __restrict__ be2,
    const float* __restrict__ m2, const float* __restrict__ v2,
    ushort* __restrict__ out2b) {
  __shared__ ushort colsA[2][64][136];  // 34.8 KB double buffer
  __shared__ float meta[9 * 64 * 8];    // 18.4 KB  (total 52 KB -> 3 blk/CU)

  const int tid = threadIdx.x;
  const int lane = tid & 63;
  const int wv = tid >> 6;
  const int lr = lane & 15, lg = lane >> 4;
  const int orig = blockIdx.x;
  const int bid = (orig & 7) * 196 + (orig >> 3);
  const int bi = bid / 196;
  const int p0 = (bid % 196) * 64;

  const ushort* src = out1b + (size_t)bi * Pp * Cc;
  const float* offb = offs + (size_t)bi * 18 * Pp;

  // ---- metadata precompute: lane = pixel, wave wv covers k = wv, wv+4, wv+8
  {
    const int p = p0 + lane;
    const int oh = p / Ww, ow = p - oh * Ww;
    for (int k = wv; k < 9; k += 4) {
      const int kdy = k / 3 - 1, kdx = k % 3 - 1;
      float py = (float)(oh + kdy) + offb[(size_t)(2 * k) * Pp + p];
      float pxf = (float)(ow + kdx) + offb[(size_t)(2 * k + 1) * Pp + p];
      float y0f = floorf(py), x0f = floorf(pxf);
      float dy = py - y0f, dx = pxf - x0f;
      int y0 = (int)y0f, x0 = (int)x0f;
      int y1 = y0 + 1, x1 = x0 + 1;
      float wy0 = (y0 >= 0 && y0 < Hh) ? 1.f - dy : 0.f;
      float wy1 = (y1 >= 0 && y1 < Hh) ? dy : 0.f;
      float wx0 = (x0 >= 0 && x0 < Ww) ? 1.f - dx : 0.f;
      float wx1 = (x1 >= 0 && x1 < Ww) ? dx : 0.f;
      int yc0 = min(max(y0, 0), Hh - 1), yc1 = min(max(y1, 0), Hh - 1);
      int xc0 = min(max(x0, 0), Ww - 1), xc1 = min(max(x1, 0), Ww - 1);
      float* mp = &meta[(k * 64 + lane) * 8];
      mp[0] = wy0 * wx0;
      mp[1] = wy0 * wx1;
      mp[2] = wy1 * wx0;
      mp[3] = wy1 * wx1;
      int* ip = (int*)(mp + 4);
      ip[0] = (yc0 * Ww + xc0) * (Cc * 2);
      ip[1] = (yc0 * Ww + xc1) * (Cc * 2);
      ip[2] = (yc1 * Ww + xc0) * (Cc * 2);
      ip[3] = (yc1 * Ww + xc1) * (Cc * 2);
    }
  }
  __syncthreads();

  f32x4 acc[4][2];
#pragma unroll
  for (int m = 0; m < 4; ++m) { acc[m][0] = (f32x4)0.f; acc[m][1] = (f32x4)0.f; }

  // gather roles: 16 lanes per pixel (4 px per wave-instruction),
  // each lane owns an 8-channel (16 B) block.
  const int pxq = lane >> 4;       // which px of the quad (0..3)
  const int l16 = lane & 15;       // 8-ch block id
  const char* sb = (const char*)src + l16 * 16;

  uint4 gv[4][4];   // [t-iter][corner] in-flight corner data
  float4 gw[4];     // [t-iter] bilinear weights

  // ISSUE: read meta, fire the 4 corner b128 loads (kept in flight)
#define ISSUE(kk, t)                                                     \
  {                                                                      \
    const int px_ = wv * 16 + (t) * 4 + pxq;                             \
    const float* mp_ = &meta[((kk) * 64 + px_) * 8];                     \
    gw[t] = *(const float4*)mp_;                                         \
    int4 o4_ = *(const int4*)(mp_ + 4);                                  \
    gv[t][0] = *(const uint4*)(sb + o4_.x);                              \
    gv[t][1] = *(const uint4*)(sb + o4_.y);                              \
    gv[t][2] = *(const uint4*)(sb + o4_.z);                              \
    gv[t][3] = *(const uint4*)(sb + o4_.w);                              \
  }

  // COMMIT: bilinear combine (8 ch), pack bf16, one ds_write_b128
#define COMMIT(buf, t)                                                   \
  {                                                                      \
    const int px_ = wv * 16 + (t) * 4 + pxq;                             \
    float4 w4_ = gw[t];                                                  \
    uint4 pk_;                                                           \
    uint* pkp_ = (uint*)&pk_;                                            \
    _Pragma("unroll")                                                    \
    for (int j = 0; j < 4; ++j) {                                        \
      uint a0_ = ((const uint*)&gv[t][0])[j];                            \
      uint a1_ = ((const uint*)&gv[t][1])[j];                            \
      uint a2_ = ((const uint*)&gv[t][2])[j];                            \
      uint a3_ = ((const uint*)&gv[t][3])[j];                            \
      float lo_ = w4_.x * bfLO(a0_) + w4_.y * bfLO(a1_)                  \
                + w4_.z * bfLO(a2_) + w4_.w * bfLO(a3_);                 \
      float hi_ = w4_.x * bfHI(a0_) + w4_.y * bfHI(a1_)                  \
                + w4_.z * bfHI(a2_) + w4_.w * bfHI(a3_);                 \
      pkp_[j] = cvtpk(lo_, hi_);                                         \
    }                                                                    \
    *(uint4*)&colsA[buf][px_][l16 * 8] = pk_;                            \
  }

  // ---- prologue: stage k=0 into buffer 0
  ISSUE(0, 0) ISSUE(0, 1) ISSUE(0, 2) ISSUE(0, 3)
  COMMIT(0, 0) COMMIT(0, 1) COMMIT(0, 2) COMMIT(0, 3)
  __syncthreads();

  for (int k = 0; k < 9; ++k) {
    const int cur = k & 1;
    const int nxt = cur ^ 1;
    const ushort* wk = wdb + (size_t)k * Cc * Cc + (size_t)(wv * 32) * Cc;

    // issue first half of k+1's gather (latency hides under MFMAs below)
    if (k < 8) { ISSUE(k + 1, 0) ISSUE(k + 1, 1) }

    // ---- MFMA half 1 (ks = 0,1) on buffer `cur`
#pragma unroll
    for (int ks = 0; ks < 2; ++ks) {
      short8 b0 = *(const short8*)(wk + lr * Cc + ks * 32 + 8 * lg);
      short8 b1v = *(const short8*)(wk + (16 + lr) * Cc + ks * 32 + 8 * lg);
#pragma unroll
      for (int m = 0; m < 4; ++m) {
        short8 a = *(const short8*)&colsA[cur][m * 16 + lr][ks * 32 + 8 * lg];
        acc[m][0] = __builtin_amdgcn_mfma_f32_16x16x32_bf16(a, b0, acc[m][0], 0, 0, 0);
        acc[m][1] = __builtin_amdgcn_mfma_f32_16x16x32_bf16(a, b1v, acc[m][1], 0, 0, 0);
      }
    }

    // commit half 1 into `nxt`, issue second half
    if (k < 8) { COMMIT(nxt, 0) COMMIT(nxt, 1) ISSUE(k + 1, 2) ISSUE(k + 1, 3) }

    // ---- MFMA half 2 (ks = 2,3) on buffer `cur`
#pragma unroll
    for (int ks = 2; ks < 4; ++ks) {
      short8 b0 = *(const short8*)(wk + lr * Cc + ks * 32 + 8 * lg);
      short8 b1v = *(const short8*)(wk + (16 + lr) * Cc + ks * 32 + 8 * lg);
#pragma unroll
      for (int m = 0; m < 4; ++m) {
        short8 a = *(const short8*)&colsA[cur][m * 16 + lr][ks * 32 + 8 * lg];
        acc[m][0] = __builtin_amdgcn_mfma_f32_16x16x32_bf16(a, b0, acc[m][0], 0, 0, 0);
        acc[m][1] = __builtin_amdgcn_mfma_f32_16x16x32_bf16(a, b1v, acc[m][1], 0, 0, 0);
      }
    }

    if (k < 8) { COMMIT(nxt, 2) COMMIT(nxt, 3) }
    __syncthreads();
  }

#undef ISSUE
#undef COMMIT

#pragma unroll
  for (int n = 0; n < 2; ++n) {
    int oc = wv * 32 + n * 16 + lr;
    float inv = g2[oc] * rsqrtf(v2[oc] + EPSf);
    float sh = (bd[oc] - m2[oc]) * inv + be2[oc];
#pragma unroll
    for (int m = 0; m < 4; ++m) {
#pragma unroll
      for (int r = 0; r < 4; ++r) {
        int p = p0 + m * 16 + lg * 4 + r;
        out2b[((size_t)bi * Pp + p) * Cc + oc] = f2bf(acc[m][n][r] * inv + sh);
      }
    }
  }
}

// ---------------------------------------------------------------------------
// k4: 1x1 conv (128->512) + bn3 + residual + relu via MFMA.
// 3136 blocks of 256px x 64oc (wave = 64px slice x 64 oc, acc 4x4).
__global__ __launch_bounds__(256, 2) void k4_mfma(
    const ushort* __restrict__ out2b, const ushort* __restrict__ w2b,
    const float* __restrict__ b2, const float* __restrict__ g3,
    const float* __restrict__ be3, const float* __restrict__ m3,
    const float* __restrict__ v3, const float* __restrict__ x,
    float* __restrict__ out) {
  const int tid = threadIdx.x;
  const int lane = tid & 63;
  const int wv = tid >> 6;
  const int lr = lane & 15, lg = lane >> 4;
  const int orig = blockIdx.x;
  const int bid = (orig & 7) * 392 + (orig >> 3);   // bijective: 3136 = 8*392
  const int bi = bid / 392;
  const int r392 = bid % 392;
  const int oc_t = r392 / 49;                        // 0..7: 64-oc tile
  const int p0 = (r392 % 49) * 256 + wv * 64;        // wave's 64-px slice
  const int ocb = oc_t * 64;

  const ushort* A = out2b + ((size_t)bi * Pp + p0) * Cc;
  const ushort* Bw = w2b + (size_t)ocb * Cc;

  // prefetch residual x: 4 n-frags x 4 m quads, in flight through the MFMAs
  float4 xv[4][4];
#pragma unroll
  for (int n = 0; n < 4; ++n) {
    int oc = ocb + n * 16 + lr;
    const float* xr = x + ((size_t)bi * IC + oc) * Pp + p0 + lg * 4;
#pragma unroll
    for (int m = 0; m < 4; ++m) xv[n][m] = *(const float4*)(xr + m * 16);
  }

  f32x4 acc[4][4];
#pragma unroll
  for (int m = 0; m < 4; ++m)
#pragma unroll
    for (int n = 0; n < 4; ++n) acc[m][n] = (f32x4)0.f;

#pragma unroll
  for (int ks = 0; ks < 4; ++ks) {
    short8 a[4];
#pragma unroll
    for (int m = 0; m < 4; ++m)
      a[m] = *(const short8*)(A + (size_t)(m * 16 + lr) * Cc + ks * 32 + 8 * lg);
#pragma unroll
    for (int n = 0; n < 4; ++n) {
      short8 b = *(const short8*)(Bw + (size_t)(n * 16 + lr) * Cc + ks * 32 + 8 * lg);
#pragma unroll
      for (int m = 0; m < 4; ++m)
        acc[m][n] = __builtin_amdgcn_mfma_f32_16x16x32_bf16(a[m], b, acc[m][n], 0, 0, 0);
    }
  }

#pragma unroll
  for (int n = 0; n < 4; ++n) {
    int oc = ocb + n * 16 + lr;
    float inv = g3[oc] * rsqrtf(v3[oc] + EPSf);
    float sh = (b2[oc] - m3[oc]) * inv + be3[oc];
    float* orow = out + ((size_t)bi * IC + oc) * Pp + p0 + lg * 4;
#pragma unroll
    for (int m = 0; m < 4; ++m) {
      float4 o;
      o.x = fmaxf(acc[m][n][0] * inv + sh + xv[n][m].x, 0.f);
      o.y = fmaxf(acc[m][n][1] * inv + sh + xv[n][m].y, 0.f);
      o.z = fmaxf(acc[m][n][2] * inv + sh + xv[n][m].z, 0.f);
      o.w = fmaxf(acc[m][n][3] * inv + sh + xv[n][m].w, 0.f);
      *(float4*)(orow + m * 16) = o;
    }
  }
}

// ---------------------------------------------------------------------------
extern "C" void kernel_launch(void* const* d_in, const int* in_sizes, int n_in,
                              void* d_out, int out_size, void* d_ws, size_t ws_size,
                              hipStream_t stream) {
  const float* x    = (const float*)d_in[0];
  const float* w1   = (const float*)d_in[1];
  const float* b1   = (const float*)d_in[2];
  const float* g1   = (const float*)d_in[3];
  const float* be1  = (const float*)d_in[4];
  const float* m1   = (const float*)d_in[5];
  const float* v1   = (const float*)d_in[6];
  const float* woff = (const float*)d_in[7];
  const float* boff = (const float*)d_in[8];
  const float* wd   = (const float*)d_in[9];
  const float* bd   = (const float*)d_in[10];
  const float* g2   = (const float*)d_in[11];
  const float* be2  = (const float*)d_in[12];
  const float* m2   = (const float*)d_in[13];
  const float* v2   = (const float*)d_in[14];
  const float* w2   = (const float*)d_in[15];
  const float* b2   = (const float*)d_in[16];
  const float* g3   = (const float*)d_in[17];
  const float* be3  = (const float*)d_in[18];
  const float* m3   = (const float*)d_in[19];
  const float* v3   = (const float*)d_in[20];

  float* ws   = (float*)d_ws;
  float* out  = (float*)d_out;
  float*  offs  = ws + OFS_OFFS;
  ushort* out2b = (ushort*)(ws + OFS_OUT2B);
  ushort* w1b   = (ushort*)(ws + OFS_W1B);
  ushort* w2b   = (ushort*)(ws + OFS_W2B);
  ushort* wdb   = (ushort*)(ws + OFS_WDB);
  ushort* wofb  = (ushort*)(ws + OFS_WOFB);
  ushort* out1b = (ushort*)d_out;                // scratch in d_out (k4 rewrites all)

  prep_kernel<<<512, 256, 0, stream>>>(w1, w2, wd, woff, ws);
  k1_fused_mfma<<<Bn * 196, 256, 0, stream>>>(x, w1b, b1, g1, be1, m1, v1, out1b);
  k2_offset_mfma<<<Bn * 49, 256, 0, stream>>>(out1b, wofb, boff, offs);
  k3_deform_mfma<<<Bn * 196, 256, 0, stream>>>(out1b, offs, wdb, bd,
                                               g2, be2, m2, v2, out2b);
  k4_mfma<<<Bn * 392, 256, 0, stream>>>(out2b, w2b, b2, g3, be3, m3, v3, x, out);
}

// Round 2
// 330.463 us; speedup vs baseline: 1.1305x; 1.0754x over previous
//
#include <hip/hip_runtime.h>
#include <hip/hip_bf16.h>

// ---------------------------------------------------------------------------
// Deformable bottleneck. Round 9:
//   - k4 epilogue re-layout via LDS: x-residual reads and out stores become
//     1-KB-contiguous per wave instruction (was 16 scattered 64-B segments).
//     acc -> LDS [16][260] f32 (pad 260 => bank-balanced fragment dump),
//     row-major re-read, +x, relu, 1KB contiguous stores. x prefetched in the
//     row-major geometry before the MFMA phase.
//   prep : weight casts (w1b, w2b, wdb, wofb all bf16)
//   k1   : x -> 1x1 conv (512->128)+bn1+relu, MFMA -> out1b (NHWC bf16, d_out)
//   k2   : 3x3 offset conv (128->18), MFMA im2col -> offs (CHW f32)
//   k3   : deformable 3x3 (128->128)+bn2, im2col-in-LDS + MFMA -> out2b
//   k4   : 1x1 conv (128->512)+bn3+residual+relu, MFMA -> d_out (CHW f32)
// out1b lives in d_out's first 25.7 MB (d_out fully rewritten by k4).
// ---------------------------------------------------------------------------

typedef __attribute__((ext_vector_type(8))) short short8;  // 8 bf16 = 4 VGPR
typedef __attribute__((ext_vector_type(4))) float f32x4;

constexpr int Bn = 8;
constexpr int IC = 512;
constexpr int Cc = 128;
constexpr int Hh = 112;
constexpr int Ww = 112;
constexpr int Pp = Hh * Ww;          // 12544
constexpr float EPSf = 1e-5f;

// workspace layout (float units)
constexpr size_t OFS_OFFS  = 0;                                 // f32[8*18*12544] (7.2 MB)
constexpr size_t OFS_OUT2B = 2097152;                           // ushort[8*12544*128] (25.7 MB)
constexpr size_t OFS_W1B   = (size_t)Bn * Pp * IC / 2;          // ushort[128*512]
constexpr size_t OFS_W2B   = OFS_W1B + (size_t)Cc * IC / 2;     // ushort[512*128]
constexpr size_t OFS_WDB   = OFS_W2B + (size_t)IC * Cc / 2;     // ushort[9*128*128] (k,oc,ic)
constexpr size_t OFS_WOFB  = OFS_WDB + (size_t)9 * Cc * Cc / 2; // ushort[9*32*128]  (k,oc,ic)

__device__ __forceinline__ ushort f2bf(float f) {   // round-to-nearest-even
  uint u = __float_as_uint(f);
  return (ushort)((u + 0x7fffu + ((u >> 16) & 1u)) >> 16);
}
__device__ __forceinline__ float bfLO(uint u) {     // f32 of low bf16
  return __uint_as_float(u << 16);
}
__device__ __forceinline__ float bfHI(uint u) {     // f32 of high bf16
  return __uint_as_float(u & 0xffff0000u);
}
__device__ __forceinline__ uint cvtpk(float a, float b) {  // (a:lo, b:hi) bf16 pair
  __hip_bfloat162 h = __float22bfloat162_rn(make_float2(a, b));
  return *(uint*)&h;
}

// ---------------------------------------------------------------------------
__global__ __launch_bounds__(256) void prep_kernel(
    const float* __restrict__ w1, const float* __restrict__ w2,
    const float* __restrict__ wd, const float* __restrict__ woff,
    float* __restrict__ ws) {
  ushort* w1b  = (ushort*)(ws + OFS_W1B);
  ushort* w2b  = (ushort*)(ws + OFS_W2B);
  ushort* wdb  = (ushort*)(ws + OFS_WDB);
  ushort* wofb = (ushort*)(ws + OFS_WOFB);
  const int n1 = Cc * IC;          // w1b  (w1 already [oc][ic])
  const int n2 = IC * Cc;          // w2b  (w2 already [oc][ic])
  const int n3 = 9 * Cc * Cc;      // wdb  [k][oc][ic]
  const int n4 = 9 * 32 * Cc;      // wofb [k][oc(pad32)][ic]
  const int total = n1 + n2 + n3 + n4;
  for (int idx = blockIdx.x * blockDim.x + threadIdx.x; idx < total;
       idx += gridDim.x * blockDim.x) {
    if (idx < n1) {
      w1b[idx] = f2bf(w1[idx]);
    } else if (idx < n1 + n2) {
      int t = idx - n1;
      w2b[t] = f2bf(w2[t]);
    } else if (idx < n1 + n2 + n3) {
      int t = idx - n1 - n2;
      int k = t / (Cc * Cc), r = t % (Cc * Cc);
      int oc = r / Cc, ic = r % Cc;
      wdb[t] = f2bf(wd[(oc * Cc + ic) * 9 + k]);
    } else {
      int t = idx - n1 - n2 - n3;
      int k = t / (32 * Cc), r = t % (32 * Cc);
      int oc = r / Cc, ic = r % Cc;
      wofb[t] = (oc < 18) ? f2bf(woff[(oc * Cc + ic) * 9 + k]) : (ushort)0;
    }
  }
}

// ---------------------------------------------------------------------------
// k1: fused transpose + 1x1 conv (512->128) + bn1 + relu via MFMA.
// Reads x f32 CHW directly; stages 128-ic chunks transposed+bf16 into LDS.
__global__ __launch_bounds__(256) void k1_fused_mfma(
    const float* __restrict__ x, const ushort* __restrict__ w1b,
    const float* __restrict__ b1, const float* __restrict__ g1,
    const float* __restrict__ be1, const float* __restrict__ m1,
    const float* __restrict__ v1, ushort* __restrict__ out1b) {
  __shared__ ushort At[64][136];   // [px][ic within chunk], padded (17.4 KB)

  const int tid = threadIdx.x;
  const int lane = tid & 63;
  const int wv = tid >> 6;
  const int lr = lane & 15, lg = lane >> 4;
  const int orig = blockIdx.x;
  const int bid = (orig & 7) * 196 + (orig >> 3);   // bijective XCD chunk swizzle
  const int bi = bid / 196;
  const int p0 = (bid % 196) * 64;

  // staging role: thread handles ic pair (ic2, ic2+1), px quads (t&3)*4 + 16i
  const int ic2 = (tid >> 2) * 2;
  const int pq = (tid & 3) * 4;

  const ushort* Bw = w1b + (size_t)(wv * 32) * IC;
  const float* xbase = x + (size_t)bi * IC * Pp + p0 + pq;

  f32x4 acc[4][2];
#pragma unroll
  for (int m = 0; m < 4; ++m) { acc[m][0] = (f32x4)0.f; acc[m][1] = (f32x4)0.f; }

  float4 pv0[4], pv1[4];
  {
    const float* r0 = xbase + (size_t)ic2 * Pp;
    const float* r1 = r0 + Pp;
#pragma unroll
    for (int i = 0; i < 4; ++i) {
      pv0[i] = *(const float4*)(r0 + 16 * i);
      pv1[i] = *(const float4*)(r1 + 16 * i);
    }
  }

#pragma unroll
  for (int ch = 0; ch < 4; ++ch) {
    const int c0 = ch * 128;
    // ---- write staged regs -> At (packed bf16 pairs)
#pragma unroll
    for (int i = 0; i < 4; ++i) {
      int px = pq + 16 * i;
      *(uint*)&At[px + 0][ic2] = cvtpk(pv0[i].x, pv1[i].x);
      *(uint*)&At[px + 1][ic2] = cvtpk(pv0[i].y, pv1[i].y);
      *(uint*)&At[px + 2][ic2] = cvtpk(pv0[i].z, pv1[i].z);
      *(uint*)&At[px + 3][ic2] = cvtpk(pv0[i].w, pv1[i].w);
    }
    __syncthreads();

    // ---- prefetch next chunk (in flight during MFMA below)
    if (ch < 3) {
      const float* r0 = xbase + (size_t)(c0 + 128 + ic2) * Pp;
      const float* r1 = r0 + Pp;
#pragma unroll
      for (int i = 0; i < 4; ++i) {
        pv0[i] = *(const float4*)(r0 + 16 * i);
        pv1[i] = *(const float4*)(r1 + 16 * i);
      }
    }

    // ---- MFMA over this 128-ic chunk
#pragma unroll
    for (int ks = 0; ks < 4; ++ks) {
      short8 b0 = *(const short8*)(Bw + (size_t)lr * IC + c0 + ks * 32 + 8 * lg);
      short8 b1v = *(const short8*)(Bw + (size_t)(16 + lr) * IC + c0 + ks * 32 + 8 * lg);
#pragma unroll
      for (int m = 0; m < 4; ++m) {
        short8 a = *(const short8*)&At[m * 16 + lr][ks * 32 + 8 * lg];
        acc[m][0] = __builtin_amdgcn_mfma_f32_16x16x32_bf16(a, b0, acc[m][0], 0, 0, 0);
        acc[m][1] = __builtin_amdgcn_mfma_f32_16x16x32_bf16(a, b1v, acc[m][1], 0, 0, 0);
      }
    }
    __syncthreads();
  }

#pragma unroll
  for (int n = 0; n < 2; ++n) {
    int oc = wv * 32 + n * 16 + lr;
    float inv = g1[oc] * rsqrtf(v1[oc] + EPSf);
    float sh = (b1[oc] - m1[oc]) * inv + be1[oc];
#pragma unroll
    for (int m = 0; m < 4; ++m) {
#pragma unroll
      for (int r = 0; r < 4; ++r) {
        int p = p0 + m * 16 + lg * 4 + r;
        out1b[((size_t)bi * Pp + p) * Cc + oc] =
            f2bf(fmaxf(acc[m][n][r] * inv + sh, 0.f));
      }
    }
  }
}

// ---------------------------------------------------------------------------
// k2: offset conv (3x3, 128->18 padded 32) via MFMA im2col.
__global__ __launch_bounds__(256) void k2_offset_mfma(
    const ushort* __restrict__ out1b, const ushort* __restrict__ wofb,
    const float* __restrict__ boff, float* __restrict__ offs) {
  const int tid = threadIdx.x;
  const int lane = tid & 63;
  const int wv = tid >> 6;
  const int lr = lane & 15, lg = lane >> 4;
  const int orig = blockIdx.x;
  const int bid = (orig & 7) * 49 + (orig >> 3);
  const int bi = bid / 49;
  const int p0 = (bid % 49) * 256 + wv * 64;   // this wave's 64 px

  const ushort* src = out1b + (size_t)bi * Pp * Cc;

  int ohm[4], owm[4];
#pragma unroll
  for (int m = 0; m < 4; ++m) {
    int p = p0 + m * 16 + lr;
    ohm[m] = p / Ww;
    owm[m] = p - ohm[m] * Ww;
  }

  f32x4 acc[4][2];
#pragma unroll
  for (int m = 0; m < 4; ++m) { acc[m][0] = (f32x4)0.f; acc[m][1] = (f32x4)0.f; }

  for (int k = 0; k < 9; ++k) {
    const int kdy = k / 3 - 1, kdx = k % 3 - 1;
    const ushort* rp[4];
    bool val[4];
#pragma unroll
    for (int m = 0; m < 4; ++m) {
      int yy = ohm[m] + kdy, xx = owm[m] + kdx;
      val[m] = ((unsigned)yy < (unsigned)Hh) && ((unsigned)xx < (unsigned)Ww);
      int yc = min(max(yy, 0), Hh - 1), xc = min(max(xx, 0), Ww - 1);
      rp[m] = src + (size_t)(yc * Ww + xc) * Cc;
    }
#pragma unroll
    for (int ks = 0; ks < 4; ++ks) {
      short8 b0 = *(const short8*)(wofb + (size_t)(k * 32 + lr) * Cc + ks * 32 + 8 * lg);
      short8 b1v = *(const short8*)(wofb + (size_t)(k * 32 + 16 + lr) * Cc + ks * 32 + 8 * lg);
#pragma unroll
      for (int m = 0; m < 4; ++m) {
        short8 av = *(const short8*)(rp[m] + ks * 32 + 8 * lg);
        short8 a = val[m] ? av : (short8)0;
        acc[m][0] = __builtin_amdgcn_mfma_f32_16x16x32_bf16(a, b0, acc[m][0], 0, 0, 0);
        acc[m][1] = __builtin_amdgcn_mfma_f32_16x16x32_bf16(a, b1v, acc[m][1], 0, 0, 0);
      }
    }
  }

#pragma unroll
  for (int n = 0; n < 2; ++n) {
    int oc = n * 16 + lr;
    if (oc < 18) {
      float bo = boff[oc];
      float* orow = offs + ((size_t)bi * 18 + oc) * Pp;
#pragma unroll
      for (int m = 0; m < 4; ++m) {
        int p = p0 + m * 16 + lg * 4;
        float4 o;
        o.x = acc[m][n][0] + bo;
        o.y = acc[m][n][1] + bo;
        o.z = acc[m][n][2] + bo;
        o.w = acc[m][n][3] + bo;
        *(float4*)(orow + p) = o;
      }
    }
  }
}

// ---------------------------------------------------------------------------
// k3: deformable conv + bn2 via im2col-in-LDS + MFMA.
// Round 8: double-buffered colsA (1 barrier/k), issue-early/combine-late
// gather pipelined across the MFMAs, 16-lane/px b128 corner loads.
__global__ __launch_bounds__(256) void k3_deform_mfma(
    const ushort* __restrict__ out1b, const float* __restrict__ offs,
    const ushort* __restrict__ wdb, const float* __restrict__ bd,
    const float* __restrict__ g2, const float* __restrict__ be2,
    const float* __restrict__ m2, const float* __restrict__ v2,
    ushort* __restrict__ out2b) {
  __shared__ ushort colsA[2][64][136];  // 34.8 KB double buffer
  __shared__ float meta[9 * 64 * 8];    // 18.4 KB  (total 52 KB -> 3 blk/CU)

  const int tid = threadIdx.x;
  const int lane = tid & 63;
  const int wv = tid >> 6;
  const int lr = lane & 15, lg = lane >> 4;
  const int orig = blockIdx.x;
  const int bid = (orig & 7) * 196 + (orig >> 3);
  const int bi = bid / 196;
  const int p0 = (bid % 196) * 64;

  const ushort* src = out1b + (size_t)bi * Pp * Cc;
  const float* offb = offs + (size_t)bi * 18 * Pp;

  // ---- metadata precompute: lane = pixel, wave wv covers k = wv, wv+4, wv+8
  {
    const int p = p0 + lane;
    const int oh = p / Ww, ow = p - oh * Ww;
    for (int k = wv; k < 9; k += 4) {
      const int kdy = k / 3 - 1, kdx = k % 3 - 1;
      float py = (float)(oh + kdy) + offb[(size_t)(2 * k) * Pp + p];
      float pxf = (float)(ow + kdx) + offb[(size_t)(2 * k + 1) * Pp + p];
      float y0f = floorf(py), x0f = floorf(pxf);
      float dy = py - y0f, dx = pxf - x0f;
      int y0 = (int)y0f, x0 = (int)x0f;
      int y1 = y0 + 1, x1 = x0 + 1;
      float wy0 = (y0 >= 0 && y0 < Hh) ? 1.f - dy : 0.f;
      float wy1 = (y1 >= 0 && y1 < Hh) ? dy : 0.f;
      float wx0 = (x0 >= 0 && x0 < Ww) ? 1.f - dx : 0.f;
      float wx1 = (x1 >= 0 && x1 < Ww) ? dx : 0.f;
      int yc0 = min(max(y0, 0), Hh - 1), yc1 = min(max(y1, 0), Hh - 1);
      int xc0 = min(max(x0, 0), Ww - 1), xc1 = min(max(x1, 0), Ww - 1);
      float* mp = &meta[(k * 64 + lane) * 8];
      mp[0] = wy0 * wx0;
      mp[1] = wy0 * wx1;
      mp[2] = wy1 * wx0;
      mp[3] = wy1 * wx1;
      int* ip = (int*)(mp + 4);
      ip[0] = (yc0 * Ww + xc0) * (Cc * 2);
      ip[1] = (yc0 * Ww + xc1) * (Cc * 2);
      ip[2] = (yc1 * Ww + xc0) * (Cc * 2);
      ip[3] = (yc1 * Ww + xc1) * (Cc * 2);
    }
  }
  __syncthreads();

  f32x4 acc[4][2];
#pragma unroll
  for (int m = 0; m < 4; ++m) { acc[m][0] = (f32x4)0.f; acc[m][1] = (f32x4)0.f; }

  // gather roles: 16 lanes per pixel (4 px per wave-instruction),
  // each lane owns an 8-channel (16 B) block.
  const int pxq = lane >> 4;       // which px of the quad (0..3)
  const int l16 = lane & 15;       // 8-ch block id
  const char* sb = (const char*)src + l16 * 16;

  uint4 gv[4][4];   // [t-iter][corner] in-flight corner data
  float4 gw[4];     // [t-iter] bilinear weights

  // ISSUE: read meta, fire the 4 corner b128 loads (kept in flight)
#define ISSUE(kk, t)                                                     \
  {                                                                      \
    const int px_ = wv * 16 + (t) * 4 + pxq;                             \
    const float* mp_ = &meta[((kk) * 64 + px_) * 8];                     \
    gw[t] = *(const float4*)mp_;                                         \
    int4 o4_ = *(const int4*)(mp_ + 4);                                  \
    gv[t][0] = *(const uint4*)(sb + o4_.x);                              \
    gv[t][1] = *(const uint4*)(sb + o4_.y);                              \
    gv[t][2] = *(const uint4*)(sb + o4_.z);                              \
    gv[t][3] = *(const uint4*)(sb + o4_.w);                              \
  }

  // COMMIT: bilinear combine (8 ch), pack bf16, one ds_write_b128
#define COMMIT(buf, t)                                                   \
  {                                                                      \
    const int px_ = wv * 16 + (t) * 4 + pxq;                             \
    float4 w4_ = gw[t];                                                  \
    uint4 pk_;                                                           \
    uint* pkp_ = (uint*)&pk_;                                            \
    _Pragma("unroll")                                                    \
    for (int j = 0; j < 4; ++j) {                                        \
      uint a0_ = ((const uint*)&gv[t][0])[j];                            \
      uint a1_ = ((const uint*)&gv[t][1])[j];                            \
      uint a2_ = ((const uint*)&gv[t][2])[j];                            \
      uint a3_ = ((const uint*)&gv[t][3])[j];                            \
      float lo_ = w4_.x * bfLO(a0_) + w4_.y * bfLO(a1_)                  \
                + w4_.z * bfLO(a2_) + w4_.w * bfLO(a3_);                 \
      float hi_ = w4_.x * bfHI(a0_) + w4_.y * bfHI(a1_)                  \
                + w4_.z * bfHI(a2_) + w4_.w * bfHI(a3_);                 \
      pkp_[j] = cvtpk(lo_, hi_);                                         \
    }                                                                    \
    *(uint4*)&colsA[buf][px_][l16 * 8] = pk_;                            \
  }

  // ---- prologue: stage k=0 into buffer 0
  ISSUE(0, 0) ISSUE(0, 1) ISSUE(0, 2) ISSUE(0, 3)
  COMMIT(0, 0) COMMIT(0, 1) COMMIT(0, 2) COMMIT(0, 3)
  __syncthreads();

  for (int k = 0; k < 9; ++k) {
    const int cur = k & 1;
    const int nxt = cur ^ 1;
    const ushort* wk = wdb + (size_t)k * Cc * Cc + (size_t)(wv * 32) * Cc;

    // issue first half of k+1's gather (latency hides under MFMAs below)
    if (k < 8) { ISSUE(k + 1, 0) ISSUE(k + 1, 1) }

    // ---- MFMA half 1 (ks = 0,1) on buffer `cur`
#pragma unroll
    for (int ks = 0; ks < 2; ++ks) {
      short8 b0 = *(const short8*)(wk + lr * Cc + ks * 32 + 8 * lg);
      short8 b1v = *(const short8*)(wk + (16 + lr) * Cc + ks * 32 + 8 * lg);
#pragma unroll
      for (int m = 0; m < 4; ++m) {
        short8 a = *(const short8*)&colsA[cur][m * 16 + lr][ks * 32 + 8 * lg];
        acc[m][0] = __builtin_amdgcn_mfma_f32_16x16x32_bf16(a, b0, acc[m][0], 0, 0, 0);
        acc[m][1] = __builtin_amdgcn_mfma_f32_16x16x32_bf16(a, b1v, acc[m][1], 0, 0, 0);
      }
    }

    // commit half 1 into `nxt`, issue second half
    if (k < 8) { COMMIT(nxt, 0) COMMIT(nxt, 1) ISSUE(k + 1, 2) ISSUE(k + 1, 3) }

    // ---- MFMA half 2 (ks = 2,3) on buffer `cur`
#pragma unroll
    for (int ks = 2; ks < 4; ++ks) {
      short8 b0 = *(const short8*)(wk + lr * Cc + ks * 32 + 8 * lg);
      short8 b1v = *(const short8*)(wk + (16 + lr) * Cc + ks * 32 + 8 * lg);
#pragma unroll
      for (int m = 0; m < 4; ++m) {
        short8 a = *(const short8*)&colsA[cur][m * 16 + lr][ks * 32 + 8 * lg];
        acc[m][0] = __builtin_amdgcn_mfma_f32_16x16x32_bf16(a, b0, acc[m][0], 0, 0, 0);
        acc[m][1] = __builtin_amdgcn_mfma_f32_16x16x32_bf16(a, b1v, acc[m][1], 0, 0, 0);
      }
    }

    if (k < 8) { COMMIT(nxt, 2) COMMIT(nxt, 3) }
    __syncthreads();
  }

#undef ISSUE
#undef COMMIT

#pragma unroll
  for (int n = 0; n < 2; ++n) {
    int oc = wv * 32 + n * 16 + lr;
    float inv = g2[oc] * rsqrtf(v2[oc] + EPSf);
    float sh = (bd[oc] - m2[oc]) * inv + be2[oc];
#pragma unroll
    for (int m = 0; m < 4; ++m) {
#pragma unroll
      for (int r = 0; r < 4; ++r) {
        int p = p0 + m * 16 + lg * 4 + r;
        out2b[((size_t)bi * Pp + p) * Cc + oc] = f2bf(acc[m][n][r] * inv + sh);
      }
    }
  }
}

// ---------------------------------------------------------------------------
// k4: 1x1 conv (128->512) + bn3 + residual + relu via MFMA.
// Round 9: 3136 blocks of 256px x 64oc. Epilogue re-layout through LDS:
//   - acc (+bn) dumped per 16-oc fragment into obuf[16][260] f32 (pad 260
//     words => the fragment-pattern ds_write_b128 is bank-balanced: 8 lanes
//     per bank-quad = LDS floor).
//   - row-major re-read: each wave instruction covers one full 1-KB oc row
//     for BOTH the x residual load and the out store (64 lanes x float4
//     contiguous) instead of 16 scattered 64-B segments.
//   - x prefetched in the row-major geometry before the MFMAs.
__global__ __launch_bounds__(256, 2) void k4_mfma(
    const ushort* __restrict__ out2b, const ushort* __restrict__ w2b,
    const float* __restrict__ b2, const float* __restrict__ g3,
    const float* __restrict__ be3, const float* __restrict__ m3,
    const float* __restrict__ v3, const float* __restrict__ x,
    float* __restrict__ out) {
  __shared__ float obuf[2][16][260];   // 33.3 KB, double-buffered per n-frag

  const int tid = threadIdx.x;
  const int lane = tid & 63;
  const int wv = tid >> 6;
  const int lr = lane & 15, lg = lane >> 4;
  const int orig = blockIdx.x;
  const int bid = (orig & 7) * 392 + (orig >> 3);   // bijective: 3136 = 8*392
  const int bi = bid / 392;
  const int r392 = bid % 392;
  const int oc_t = r392 / 49;                        // 0..7: 64-oc tile
  const int pblk = (r392 % 49) * 256;                // block px base
  const int p0 = pblk + wv * 64;                     // wave's 64-px slice (MFMA)
  const int ocb = oc_t * 64;

  const ushort* A = out2b + ((size_t)bi * Pp + p0) * Cc;
  const ushort* Bw = w2b + (size_t)ocb * Cc;

  // prefetch residual x in the row-major epilogue geometry:
  // [n][it] -> oc row = ocb + n*16 + it*4 + wv, px = pblk + lane*4
  // each instruction: 64 lanes x float4 = 1 KB contiguous.
  float4 xv[4][4];
#pragma unroll
  for (int n = 0; n < 4; ++n)
#pragma unroll
    for (int it = 0; it < 4; ++it) {
      int oc = ocb + n * 16 + it * 4 + wv;
      xv[n][it] = *(const float4*)(x + ((size_t)bi * IC + oc) * Pp + pblk + lane * 4);
    }

  f32x4 acc[4][4];
#pragma unroll
  for (int m = 0; m < 4; ++m)
#pragma unroll
    for (int n = 0; n < 4; ++n) acc[m][n] = (f32x4)0.f;

#pragma unroll
  for (int ks = 0; ks < 4; ++ks) {
    short8 a[4];
#pragma unroll
    for (int m = 0; m < 4; ++m)
      a[m] = *(const short8*)(A + (size_t)(m * 16 + lr) * Cc + ks * 32 + 8 * lg);
#pragma unroll
    for (int n = 0; n < 4; ++n) {
      short8 b = *(const short8*)(Bw + (size_t)(n * 16 + lr) * Cc + ks * 32 + 8 * lg);
#pragma unroll
      for (int m = 0; m < 4; ++m)
        acc[m][n] = __builtin_amdgcn_mfma_f32_16x16x32_bf16(a[m], b, acc[m][n], 0, 0, 0);
    }
  }

  // ---- epilogue: per n-fragment, relayout via LDS, +x, relu, 1KB stores
#pragma unroll
  for (int n = 0; n < 4; ++n) {
    {
      int ocw = ocb + n * 16 + lr;   // writer lane's oc (fragment column)
      float inv = g3[ocw] * rsqrtf(v3[ocw] + EPSf);
      float sh = (b2[ocw] - m3[ocw]) * inv + be3[ocw];
      float(*buf)[260] = obuf[n & 1];
#pragma unroll
      for (int m = 0; m < 4; ++m) {
        float4 o;
        o.x = acc[m][n][0] * inv + sh;
        o.y = acc[m][n][1] * inv + sh;
        o.z = acc[m][n][2] * inv + sh;
        o.w = acc[m][n][3] * inv + sh;
        *(float4*)&buf[lr][wv * 64 + m * 16 + lg * 4] = o;
      }
    }
    __syncthreads();
    {
      const float(*buf)[260] = obuf[n & 1];
#pragma unroll
      for (int it = 0; it < 4; ++it) {
        int r = it * 4 + wv;                 // oc row within fragment
        int oc = ocb + n * 16 + r;
        float4 v = *(const float4*)&buf[r][lane * 4];
        float4 xr = xv[n][it];
        float4 o;
        o.x = fmaxf(v.x + xr.x, 0.f);
        o.y = fmaxf(v.y + xr.y, 0.f);
        o.z = fmaxf(v.z + xr.z, 0.f);
        o.w = fmaxf(v.w + xr.w, 0.f);
        *(float4*)(out + ((size_t)bi * IC + oc) * Pp + pblk + lane * 4) = o;
      }
    }
  }
}

// ---------------------------------------------------------------------------
extern "C" void kernel_launch(void* const* d_in, const int* in_sizes, int n_in,
                              void* d_out, int out_size, void* d_ws, size_t ws_size,
                              hipStream_t stream) {
  const float* x    = (const float*)d_in[0];
  const float* w1   = (const float*)d_in[1];
  const float* b1   = (const float*)d_in[2];
  const float* g1   = (const float*)d_in[3];
  const float* be1  = (const float*)d_in[4];
  const float* m1   = (const float*)d_in[5];
  const float* v1   = (const float*)d_in[6];
  const float* woff = (const float*)d_in[7];
  const float* boff = (const float*)d_in[8];
  const float* wd   = (const float*)d_in[9];
  const float* bd   = (const float*)d_in[10];
  const float* g2   = (const float*)d_in[11];
  const float* be2  = (const float*)d_in[12];
  const float* m2   = (const float*)d_in[13];
  const float* v2   = (const float*)d_in[14];
  const float* w2   = (const float*)d_in[15];
  const float* b2   = (const float*)d_in[16];
  const float* g3   = (const float*)d_in[17];
  const float* be3  = (const float*)d_in[18];
  const float* m3   = (const float*)d_in[19];
  const float* v3   = (const float*)d_in[20];

  float* ws   = (float*)d_ws;
  float* out  = (float*)d_out;
  float*  offs  = ws + OFS_OFFS;
  ushort* out2b = (ushort*)(ws + OFS_OUT2B);
  ushort* w1b   = (ushort*)(ws + OFS_W1B);
  ushort* w2b   = (ushort*)(ws + OFS_W2B);
  ushort* wdb   = (ushort*)(ws + OFS_WDB);
  ushort* wofb  = (ushort*)(ws + OFS_WOFB);
  ushort* out1b = (ushort*)d_out;                // scratch in d_out (k4 rewrites all)

  prep_kernel<<<512, 256, 0, stream>>>(w1, w2, wd, woff, ws);
  k1_fused_mfma<<<Bn * 196, 256, 0, stream>>>(x, w1b, b1, g1, be1, m1, v1, out1b);
  k2_offset_mfma<<<Bn * 49, 256, 0, stream>>>(out1b, wofb, boff, offs);
  k3_deform_mfma<<<Bn * 196, 256, 0, stream>>>(out1b, offs, wdb, bd,
                                               g2, be2, m2, v2, out2b);
  k4_mfma<<<Bn * 392, 256, 0, stream>>>(out2b, w2b, b2, g3, be3, m3, v3, x, out);
}

// Round 3
// 323.935 us; speedup vs baseline: 1.1533x; 1.0202x over previous
//
#include <hip/hip_runtime.h>
#include <hip/hip_bf16.h>

// ---------------------------------------------------------------------------
// Deformable bottleneck. Round 10:
//   - k3: per-k __syncthreads (which drains vmcnt(0), killing the gather
//     pipeline) replaced by raw "s_waitcnt lgkmcnt(0); s_barrier" -- global
//     corner loads now stay in flight ACROSS the barrier. Pipeline deepened
//     to a full k-step: MFMA(k) | COMMIT(k+1) | ISSUE(k+2) | lgkm-barrier.
//   prep : weight casts (w1b, w2b, wdb, wofb all bf16)
//   k1   : x -> 1x1 conv (512->128)+bn1+relu, MFMA -> out1b (NHWC bf16, d_out)
//   k2   : 3x3 offset conv (128->18), MFMA im2col -> offs (CHW f32)
//   k3   : deformable 3x3 (128->128)+bn2, im2col-in-LDS + MFMA -> out2b
//   k4   : 1x1 conv (128->512)+bn3+residual+relu, MFMA -> d_out (CHW f32)
// out1b lives in d_out's first 25.7 MB (d_out fully rewritten by k4).
// ---------------------------------------------------------------------------

typedef __attribute__((ext_vector_type(8))) short short8;  // 8 bf16 = 4 VGPR
typedef __attribute__((ext_vector_type(4))) float f32x4;

constexpr int Bn = 8;
constexpr int IC = 512;
constexpr int Cc = 128;
constexpr int Hh = 112;
constexpr int Ww = 112;
constexpr int Pp = Hh * Ww;          // 12544
constexpr float EPSf = 1e-5f;

// workspace layout (float units)
constexpr size_t OFS_OFFS  = 0;                                 // f32[8*18*12544] (7.2 MB)
constexpr size_t OFS_OUT2B = 2097152;                           // ushort[8*12544*128] (25.7 MB)
constexpr size_t OFS_W1B   = (size_t)Bn * Pp * IC / 2;          // ushort[128*512]
constexpr size_t OFS_W2B   = OFS_W1B + (size_t)Cc * IC / 2;     // ushort[512*128]
constexpr size_t OFS_WDB   = OFS_W2B + (size_t)IC * Cc / 2;     // ushort[9*128*128] (k,oc,ic)
constexpr size_t OFS_WOFB  = OFS_WDB + (size_t)9 * Cc * Cc / 2; // ushort[9*32*128]  (k,oc,ic)

__device__ __forceinline__ ushort f2bf(float f) {   // round-to-nearest-even
  uint u = __float_as_uint(f);
  return (ushort)((u + 0x7fffu + ((u >> 16) & 1u)) >> 16);
}
__device__ __forceinline__ float bfLO(uint u) {     // f32 of low bf16
  return __uint_as_float(u << 16);
}
__device__ __forceinline__ float bfHI(uint u) {     // f32 of high bf16
  return __uint_as_float(u & 0xffff0000u);
}
__device__ __forceinline__ uint cvtpk(float a, float b) {  // (a:lo, b:hi) bf16 pair
  __hip_bfloat162 h = __float22bfloat162_rn(make_float2(a, b));
  return *(uint*)&h;
}

// ---------------------------------------------------------------------------
__global__ __launch_bounds__(256) void prep_kernel(
    const float* __restrict__ w1, const float* __restrict__ w2,
    const float* __restrict__ wd, const float* __restrict__ woff,
    float* __restrict__ ws) {
  ushort* w1b  = (ushort*)(ws + OFS_W1B);
  ushort* w2b  = (ushort*)(ws + OFS_W2B);
  ushort* wdb  = (ushort*)(ws + OFS_WDB);
  ushort* wofb = (ushort*)(ws + OFS_WOFB);
  const int n1 = Cc * IC;          // w1b  (w1 already [oc][ic])
  const int n2 = IC * Cc;          // w2b  (w2 already [oc][ic])
  const int n3 = 9 * Cc * Cc;      // wdb  [k][oc][ic]
  const int n4 = 9 * 32 * Cc;      // wofb [k][oc(pad32)][ic]
  const int total = n1 + n2 + n3 + n4;
  for (int idx = blockIdx.x * blockDim.x + threadIdx.x; idx < total;
       idx += gridDim.x * blockDim.x) {
    if (idx < n1) {
      w1b[idx] = f2bf(w1[idx]);
    } else if (idx < n1 + n2) {
      int t = idx - n1;
      w2b[t] = f2bf(w2[t]);
    } else if (idx < n1 + n2 + n3) {
      int t = idx - n1 - n2;
      int k = t / (Cc * Cc), r = t % (Cc * Cc);
      int oc = r / Cc, ic = r % Cc;
      wdb[t] = f2bf(wd[(oc * Cc + ic) * 9 + k]);
    } else {
      int t = idx - n1 - n2 - n3;
      int k = t / (32 * Cc), r = t % (32 * Cc);
      int oc = r / Cc, ic = r % Cc;
      wofb[t] = (oc < 18) ? f2bf(woff[(oc * Cc + ic) * 9 + k]) : (ushort)0;
    }
  }
}

// ---------------------------------------------------------------------------
// k1: fused transpose + 1x1 conv (512->128) + bn1 + relu via MFMA.
// Reads x f32 CHW directly; stages 128-ic chunks transposed+bf16 into LDS.
__global__ __launch_bounds__(256) void k1_fused_mfma(
    const float* __restrict__ x, const ushort* __restrict__ w1b,
    const float* __restrict__ b1, const float* __restrict__ g1,
    const float* __restrict__ be1, const float* __restrict__ m1,
    const float* __restrict__ v1, ushort* __restrict__ out1b) {
  __shared__ ushort At[64][136];   // [px][ic within chunk], padded (17.4 KB)

  const int tid = threadIdx.x;
  const int lane = tid & 63;
  const int wv = tid >> 6;
  const int lr = lane & 15, lg = lane >> 4;
  const int orig = blockIdx.x;
  const int bid = (orig & 7) * 196 + (orig >> 3);   // bijective XCD chunk swizzle
  const int bi = bid / 196;
  const int p0 = (bid % 196) * 64;

  // staging role: thread handles ic pair (ic2, ic2+1), px quads (t&3)*4 + 16i
  const int ic2 = (tid >> 2) * 2;
  const int pq = (tid & 3) * 4;

  const ushort* Bw = w1b + (size_t)(wv * 32) * IC;
  const float* xbase = x + (size_t)bi * IC * Pp + p0 + pq;

  f32x4 acc[4][2];
#pragma unroll
  for (int m = 0; m < 4; ++m) { acc[m][0] = (f32x4)0.f; acc[m][1] = (f32x4)0.f; }

  float4 pv0[4], pv1[4];
  {
    const float* r0 = xbase + (size_t)ic2 * Pp;
    const float* r1 = r0 + Pp;
#pragma unroll
    for (int i = 0; i < 4; ++i) {
      pv0[i] = *(const float4*)(r0 + 16 * i);
      pv1[i] = *(const float4*)(r1 + 16 * i);
    }
  }

#pragma unroll
  for (int ch = 0; ch < 4; ++ch) {
    const int c0 = ch * 128;
    // ---- write staged regs -> At (packed bf16 pairs)
#pragma unroll
    for (int i = 0; i < 4; ++i) {
      int px = pq + 16 * i;
      *(uint*)&At[px + 0][ic2] = cvtpk(pv0[i].x, pv1[i].x);
      *(uint*)&At[px + 1][ic2] = cvtpk(pv0[i].y, pv1[i].y);
      *(uint*)&At[px + 2][ic2] = cvtpk(pv0[i].z, pv1[i].z);
      *(uint*)&At[px + 3][ic2] = cvtpk(pv0[i].w, pv1[i].w);
    }
    __syncthreads();

    // ---- prefetch next chunk (in flight during MFMA below)
    if (ch < 3) {
      const float* r0 = xbase + (size_t)(c0 + 128 + ic2) * Pp;
      const float* r1 = r0 + Pp;
#pragma unroll
      for (int i = 0; i < 4; ++i) {
        pv0[i] = *(const float4*)(r0 + 16 * i);
        pv1[i] = *(const float4*)(r1 + 16 * i);
      }
    }

    // ---- MFMA over this 128-ic chunk
#pragma unroll
    for (int ks = 0; ks < 4; ++ks) {
      short8 b0 = *(const short8*)(Bw + (size_t)lr * IC + c0 + ks * 32 + 8 * lg);
      short8 b1v = *(const short8*)(Bw + (size_t)(16 + lr) * IC + c0 + ks * 32 + 8 * lg);
#pragma unroll
      for (int m = 0; m < 4; ++m) {
        short8 a = *(const short8*)&At[m * 16 + lr][ks * 32 + 8 * lg];
        acc[m][0] = __builtin_amdgcn_mfma_f32_16x16x32_bf16(a, b0, acc[m][0], 0, 0, 0);
        acc[m][1] = __builtin_amdgcn_mfma_f32_16x16x32_bf16(a, b1v, acc[m][1], 0, 0, 0);
      }
    }
    __syncthreads();
  }

#pragma unroll
  for (int n = 0; n < 2; ++n) {
    int oc = wv * 32 + n * 16 + lr;
    float inv = g1[oc] * rsqrtf(v1[oc] + EPSf);
    float sh = (b1[oc] - m1[oc]) * inv + be1[oc];
#pragma unroll
    for (int m = 0; m < 4; ++m) {
#pragma unroll
      for (int r = 0; r < 4; ++r) {
        int p = p0 + m * 16 + lg * 4 + r;
        out1b[((size_t)bi * Pp + p) * Cc + oc] =
            f2bf(fmaxf(acc[m][n][r] * inv + sh, 0.f));
      }
    }
  }
}

// ---------------------------------------------------------------------------
// k2: offset conv (3x3, 128->18 padded 32) via MFMA im2col.
__global__ __launch_bounds__(256) void k2_offset_mfma(
    const ushort* __restrict__ out1b, const ushort* __restrict__ wofb,
    const float* __restrict__ boff, float* __restrict__ offs) {
  const int tid = threadIdx.x;
  const int lane = tid & 63;
  const int wv = tid >> 6;
  const int lr = lane & 15, lg = lane >> 4;
  const int orig = blockIdx.x;
  const int bid = (orig & 7) * 49 + (orig >> 3);
  const int bi = bid / 49;
  const int p0 = (bid % 49) * 256 + wv * 64;   // this wave's 64 px

  const ushort* src = out1b + (size_t)bi * Pp * Cc;

  int ohm[4], owm[4];
#pragma unroll
  for (int m = 0; m < 4; ++m) {
    int p = p0 + m * 16 + lr;
    ohm[m] = p / Ww;
    owm[m] = p - ohm[m] * Ww;
  }

  f32x4 acc[4][2];
#pragma unroll
  for (int m = 0; m < 4; ++m) { acc[m][0] = (f32x4)0.f; acc[m][1] = (f32x4)0.f; }

  for (int k = 0; k < 9; ++k) {
    const int kdy = k / 3 - 1, kdx = k % 3 - 1;
    const ushort* rp[4];
    bool val[4];
#pragma unroll
    for (int m = 0; m < 4; ++m) {
      int yy = ohm[m] + kdy, xx = owm[m] + kdx;
      val[m] = ((unsigned)yy < (unsigned)Hh) && ((unsigned)xx < (unsigned)Ww);
      int yc = min(max(yy, 0), Hh - 1), xc = min(max(xx, 0), Ww - 1);
      rp[m] = src + (size_t)(yc * Ww + xc) * Cc;
    }
#pragma unroll
    for (int ks = 0; ks < 4; ++ks) {
      short8 b0 = *(const short8*)(wofb + (size_t)(k * 32 + lr) * Cc + ks * 32 + 8 * lg);
      short8 b1v = *(const short8*)(wofb + (size_t)(k * 32 + 16 + lr) * Cc + ks * 32 + 8 * lg);
#pragma unroll
      for (int m = 0; m < 4; ++m) {
        short8 av = *(const short8*)(rp[m] + ks * 32 + 8 * lg);
        short8 a = val[m] ? av : (short8)0;
        acc[m][0] = __builtin_amdgcn_mfma_f32_16x16x32_bf16(a, b0, acc[m][0], 0, 0, 0);
        acc[m][1] = __builtin_amdgcn_mfma_f32_16x16x32_bf16(a, b1v, acc[m][1], 0, 0, 0);
      }
    }
  }

#pragma unroll
  for (int n = 0; n < 2; ++n) {
    int oc = n * 16 + lr;
    if (oc < 18) {
      float bo = boff[oc];
      float* orow = offs + ((size_t)bi * 18 + oc) * Pp;
#pragma unroll
      for (int m = 0; m < 4; ++m) {
        int p = p0 + m * 16 + lg * 4;
        float4 o;
        o.x = acc[m][n][0] + bo;
        o.y = acc[m][n][1] + bo;
        o.z = acc[m][n][2] + bo;
        o.w = acc[m][n][3] + bo;
        *(float4*)(orow + p) = o;
      }
    }
  }
}

// ---------------------------------------------------------------------------
// k3: deformable conv + bn2 via im2col-in-LDS + MFMA.
// Round 10: counted-wait barriers (lgkmcnt only -- corner loads stay in
// flight across s_barrier) + full-k-step pipeline:
//   iter k:  MFMA(k, buf cur) | COMMIT(k+1 -> buf nxt) | ISSUE(k+2) | barrier
// Issue->consume distance is now a whole iteration (>= 400 cy >> L2 latency).
__global__ __launch_bounds__(256) void k3_deform_mfma(
    const ushort* __restrict__ out1b, const float* __restrict__ offs,
    const ushort* __restrict__ wdb, const float* __restrict__ bd,
    const float* __restrict__ g2, const float* __restrict__ be2,
    const float* __restrict__ m2, const float* __restrict__ v2,
    ushort* __restrict__ out2b) {
  __shared__ ushort colsA[2][64][136];  // 34.8 KB double buffer
  __shared__ float meta[9 * 64 * 8];    // 18.4 KB  (total 52 KB -> 3 blk/CU)

  const int tid = threadIdx.x;
  const int lane = tid & 63;
  const int wv = tid >> 6;
  const int lr = lane & 15, lg = lane >> 4;
  const int orig = blockIdx.x;
  const int bid = (orig & 7) * 196 + (orig >> 3);
  const int bi = bid / 196;
  const int p0 = (bid % 196) * 64;

  const ushort* src = out1b + (size_t)bi * Pp * Cc;
  const float* offb = offs + (size_t)bi * 18 * Pp;

  // ---- metadata precompute: lane = pixel, wave wv covers k = wv, wv+4, wv+8
  {
    const int p = p0 + lane;
    const int oh = p / Ww, ow = p - oh * Ww;
    for (int k = wv; k < 9; k += 4) {
      const int kdy = k / 3 - 1, kdx = k % 3 - 1;
      float py = (float)(oh + kdy) + offb[(size_t)(2 * k) * Pp + p];
      float pxf = (float)(ow + kdx) + offb[(size_t)(2 * k + 1) * Pp + p];
      float y0f = floorf(py), x0f = floorf(pxf);
      float dy = py - y0f, dx = pxf - x0f;
      int y0 = (int)y0f, x0 = (int)x0f;
      int y1 = y0 + 1, x1 = x0 + 1;
      float wy0 = (y0 >= 0 && y0 < Hh) ? 1.f - dy : 0.f;
      float wy1 = (y1 >= 0 && y1 < Hh) ? dy : 0.f;
      float wx0 = (x0 >= 0 && x0 < Ww) ? 1.f - dx : 0.f;
      float wx1 = (x1 >= 0 && x1 < Ww) ? dx : 0.f;
      int yc0 = min(max(y0, 0), Hh - 1), yc1 = min(max(y1, 0), Hh - 1);
      int xc0 = min(max(x0, 0), Ww - 1), xc1 = min(max(x1, 0), Ww - 1);
      float* mp = &meta[(k * 64 + lane) * 8];
      mp[0] = wy0 * wx0;
      mp[1] = wy0 * wx1;
      mp[2] = wy1 * wx0;
      mp[3] = wy1 * wx1;
      int* ip = (int*)(mp + 4);
      ip[0] = (yc0 * Ww + xc0) * (Cc * 2);
      ip[1] = (yc0 * Ww + xc1) * (Cc * 2);
      ip[2] = (yc1 * Ww + xc0) * (Cc * 2);
      ip[3] = (yc1 * Ww + xc1) * (Cc * 2);
    }
  }
  __syncthreads();

  f32x4 acc[4][2];
#pragma unroll
  for (int m = 0; m < 4; ++m) { acc[m][0] = (f32x4)0.f; acc[m][1] = (f32x4)0.f; }

  // gather roles: 16 lanes per pixel (4 px per wave-instruction),
  // each lane owns an 8-channel (16 B) block.
  const int pxq = lane >> 4;       // which px of the quad (0..3)
  const int l16 = lane & 15;       // 8-ch block id
  const char* sb = (const char*)src + l16 * 16;

  uint4 gv[4][4];   // [t-iter][corner] in-flight corner data
  float4 gw[4];     // [t-iter] bilinear weights

  // LDS-only barrier: orders ds ops across waves WITHOUT draining vmcnt,
  // so the global corner loads issued for k+2 survive the barrier in flight.
#define BAR_LGKM asm volatile("s_waitcnt lgkmcnt(0)\ns_barrier" ::: "memory")

  // ISSUE: read meta, fire the 4 corner b128 loads (kept in flight)
#define ISSUE(kk, t)                                                     \
  {                                                                      \
    const int px_ = wv * 16 + (t) * 4 + pxq;                             \
    const float* mp_ = &meta[((kk) * 64 + px_) * 8];                     \
    gw[t] = *(const float4*)mp_;                                         \
    int4 o4_ = *(const int4*)(mp_ + 4);                                  \
    gv[t][0] = *(const uint4*)(sb + o4_.x);                              \
    gv[t][1] = *(const uint4*)(sb + o4_.y);                              \
    gv[t][2] = *(const uint4*)(sb + o4_.z);                              \
    gv[t][3] = *(const uint4*)(sb + o4_.w);                              \
  }

  // COMMIT: bilinear combine (8 ch), pack bf16, one ds_write_b128
#define COMMIT(buf, t)                                                   \
  {                                                                      \
    const int px_ = wv * 16 + (t) * 4 + pxq;                             \
    float4 w4_ = gw[t];                                                  \
    uint4 pk_;                                                           \
    uint* pkp_ = (uint*)&pk_;                                            \
    _Pragma("unroll")                                                    \
    for (int j = 0; j < 4; ++j) {                                        \
      uint a0_ = ((const uint*)&gv[t][0])[j];                            \
      uint a1_ = ((const uint*)&gv[t][1])[j];                            \
      uint a2_ = ((const uint*)&gv[t][2])[j];                            \
      uint a3_ = ((const uint*)&gv[t][3])[j];                            \
      float lo_ = w4_.x * bfLO(a0_) + w4_.y * bfLO(a1_)                  \
                + w4_.z * bfLO(a2_) + w4_.w * bfLO(a3_);                 \
      float hi_ = w4_.x * bfHI(a0_) + w4_.y * bfHI(a1_)                  \
                + w4_.z * bfHI(a2_) + w4_.w * bfHI(a3_);                 \
      pkp_[j] = cvtpk(lo_, hi_);                                         \
    }                                                                    \
    *(uint4*)&colsA[buf][px_][l16 * 8] = pk_;                            \
  }

  // ---- prologue: stage k=0 into buffer 0 (one serial stall), issue k=1
  ISSUE(0, 0) ISSUE(0, 1) ISSUE(0, 2) ISSUE(0, 3)
  COMMIT(0, 0) COMMIT(0, 1) COMMIT(0, 2) COMMIT(0, 3)
  ISSUE(1, 0) ISSUE(1, 1) ISSUE(1, 2) ISSUE(1, 3)
  BAR_LGKM;

  for (int k = 0; k < 9; ++k) {
    const int cur = k & 1;
    const int nxt = cur ^ 1;
    const ushort* wk = wdb + (size_t)k * Cc * Cc + (size_t)(wv * 32) * Cc;

    // ---- MFMA phase: all 16 on buffer `cur`
#pragma unroll
    for (int ks = 0; ks < 4; ++ks) {
      short8 b0 = *(const short8*)(wk + lr * Cc + ks * 32 + 8 * lg);
      short8 b1v = *(const short8*)(wk + (16 + lr) * Cc + ks * 32 + 8 * lg);
#pragma unroll
      for (int m = 0; m < 4; ++m) {
        short8 a = *(const short8*)&colsA[cur][m * 16 + lr][ks * 32 + 8 * lg];
        acc[m][0] = __builtin_amdgcn_mfma_f32_16x16x32_bf16(a, b0, acc[m][0], 0, 0, 0);
        acc[m][1] = __builtin_amdgcn_mfma_f32_16x16x32_bf16(a, b1v, acc[m][1], 0, 0, 0);
      }
    }

    // ---- commit k+1 (loads issued a full iteration ago), refill with k+2
    if (k < 8) {
      COMMIT(nxt, 0)
      if (k < 7) { ISSUE(k + 2, 0) }
      COMMIT(nxt, 1)
      if (k < 7) { ISSUE(k + 2, 1) }
      COMMIT(nxt, 2)
      if (k < 7) { ISSUE(k + 2, 2) }
      COMMIT(nxt, 3)
      if (k < 7) { ISSUE(k + 2, 3) }
      BAR_LGKM;
    }
  }

#undef ISSUE
#undef COMMIT
#undef BAR_LGKM

#pragma unroll
  for (int n = 0; n < 2; ++n) {
    int oc = wv * 32 + n * 16 + lr;
    float inv = g2[oc] * rsqrtf(v2[oc] + EPSf);
    float sh = (bd[oc] - m2[oc]) * inv + be2[oc];
#pragma unroll
    for (int m = 0; m < 4; ++m) {
#pragma unroll
      for (int r = 0; r < 4; ++r) {
        int p = p0 + m * 16 + lg * 4 + r;
        out2b[((size_t)bi * Pp + p) * Cc + oc] = f2bf(acc[m][n][r] * inv + sh);
      }
    }
  }
}

// ---------------------------------------------------------------------------
// k4: 1x1 conv (128->512) + bn3 + residual + relu via MFMA.
// Round 9: 3136 blocks of 256px x 64oc. Epilogue re-layout through LDS:
//   - acc (+bn) dumped per 16-oc fragment into obuf[16][260] f32 (pad 260
//     words => the fragment-pattern ds_write_b128 is bank-balanced: 8 lanes
//     per bank-quad = LDS floor).
//   - row-major re-read: each wave instruction covers one full 1-KB oc row
//     for BOTH the x residual load and the out store (64 lanes x float4
//     contiguous) instead of 16 scattered 64-B segments.
//   - x prefetched in the row-major geometry before the MFMAs.
__global__ __launch_bounds__(256, 2) void k4_mfma(
    const ushort* __restrict__ out2b, const ushort* __restrict__ w2b,
    const float* __restrict__ b2, const float* __restrict__ g3,
    const float* __restrict__ be3, const float* __restrict__ m3,
    const float* __restrict__ v3, const float* __restrict__ x,
    float* __restrict__ out) {
  __shared__ float obuf[2][16][260];   // 33.3 KB, double-buffered per n-frag

  const int tid = threadIdx.x;
  const int lane = tid & 63;
  const int wv = tid >> 6;
  const int lr = lane & 15, lg = lane >> 4;
  const int orig = blockIdx.x;
  const int bid = (orig & 7) * 392 + (orig >> 3);   // bijective: 3136 = 8*392
  const int bi = bid / 392;
  const int r392 = bid % 392;
  const int oc_t = r392 / 49;                        // 0..7: 64-oc tile
  const int pblk = (r392 % 49) * 256;                // block px base
  const int p0 = pblk + wv * 64;                     // wave's 64-px slice (MFMA)
  const int ocb = oc_t * 64;

  const ushort* A = out2b + ((size_t)bi * Pp + p0) * Cc;
  const ushort* Bw = w2b + (size_t)ocb * Cc;

  // prefetch residual x in the row-major epilogue geometry:
  // [n][it] -> oc row = ocb + n*16 + it*4 + wv, px = pblk + lane*4
  // each instruction: 64 lanes x float4 = 1 KB contiguous.
  float4 xv[4][4];
#pragma unroll
  for (int n = 0; n < 4; ++n)
#pragma unroll
    for (int it = 0; it < 4; ++it) {
      int oc = ocb + n * 16 + it * 4 + wv;
      xv[n][it] = *(const float4*)(x + ((size_t)bi * IC + oc) * Pp + pblk + lane * 4);
    }

  f32x4 acc[4][4];
#pragma unroll
  for (int m = 0; m < 4; ++m)
#pragma unroll
    for (int n = 0; n < 4; ++n) acc[m][n] = (f32x4)0.f;

#pragma unroll
  for (int ks = 0; ks < 4; ++ks) {
    short8 a[4];
#pragma unroll
    for (int m = 0; m < 4; ++m)
      a[m] = *(const short8*)(A + (size_t)(m * 16 + lr) * Cc + ks * 32 + 8 * lg);
#pragma unroll
    for (int n = 0; n < 4; ++n) {
      short8 b = *(const short8*)(Bw + (size_t)(n * 16 + lr) * Cc + ks * 32 + 8 * lg);
#pragma unroll
      for (int m = 0; m < 4; ++m)
        acc[m][n] = __builtin_amdgcn_mfma_f32_16x16x32_bf16(a[m], b, acc[m][n], 0, 0, 0);
    }
  }

  // ---- epilogue: per n-fragment, relayout via LDS, +x, relu, 1KB stores
#pragma unroll
  for (int n = 0; n < 4; ++n) {
    {
      int ocw = ocb + n * 16 + lr;   // writer lane's oc (fragment column)
      float inv = g3[ocw] * rsqrtf(v3[ocw] + EPSf);
      float sh = (b2[ocw] - m3[ocw]) * inv + be3[ocw];
      float(*buf)[260] = obuf[n & 1];
#pragma unroll
      for (int m = 0; m < 4; ++m) {
        float4 o;
        o.x = acc[m][n][0] * inv + sh;
        o.y = acc[m][n][1] * inv + sh;
        o.z = acc[m][n][2] * inv + sh;
        o.w = acc[m][n][3] * inv + sh;
        *(float4*)&buf[lr][wv * 64 + m * 16 + lg * 4] = o;
      }
    }
    __syncthreads();
    {
      const float(*buf)[260] = obuf[n & 1];
#pragma unroll
      for (int it = 0; it < 4; ++it) {
        int r = it * 4 + wv;                 // oc row within fragment
        int oc = ocb + n * 16 + r;
        float4 v = *(const float4*)&buf[r][lane * 4];
        float4 xr = xv[n][it];
        float4 o;
        o.x = fmaxf(v.x + xr.x, 0.f);
        o.y = fmaxf(v.y + xr.y, 0.f);
        o.z = fmaxf(v.z + xr.z, 0.f);
        o.w = fmaxf(v.w + xr.w, 0.f);
        *(float4*)(out + ((size_t)bi * IC + oc) * Pp + pblk + lane * 4) = o;
      }
    }
  }
}

// ---------------------------------------------------------------------------
extern "C" void kernel_launch(void* const* d_in, const int* in_sizes, int n_in,
                              void* d_out, int out_size, void* d_ws, size_t ws_size,
                              hipStream_t stream) {
  const float* x    = (const float*)d_in[0];
  const float* w1   = (const float*)d_in[1];
  const float* b1   = (const float*)d_in[2];
  const float* g1   = (const float*)d_in[3];
  const float* be1  = (const float*)d_in[4];
  const float* m1   = (const float*)d_in[5];
  const float* v1   = (const float*)d_in[6];
  const float* woff = (const float*)d_in[7];
  const float* boff = (const float*)d_in[8];
  const float* wd   = (const float*)d_in[9];
  const float* bd   = (const float*)d_in[10];
  const float* g2   = (const float*)d_in[11];
  const float* be2  = (const float*)d_in[12];
  const float* m2   = (const float*)d_in[13];
  const float* v2   = (const float*)d_in[14];
  const float* w2   = (const float*)d_in[15];
  const float* b2   = (const float*)d_in[16];
  const float* g3   = (const float*)d_in[17];
  const float* be3  = (const float*)d_in[18];
  const float* m3   = (const float*)d_in[19];
  const float* v3   = (const float*)d_in[20];

  float* ws   = (float*)d_ws;
  float* out  = (float*)d_out;
  float*  offs  = ws + OFS_OFFS;
  ushort* out2b = (ushort*)(ws + OFS_OUT2B);
  ushort* w1b   = (ushort*)(ws + OFS_W1B);
  ushort* w2b   = (ushort*)(ws + OFS_W2B);
  ushort* wdb   = (ushort*)(ws + OFS_WDB);
  ushort* wofb  = (ushort*)(ws + OFS_WOFB);
  ushort* out1b = (ushort*)d_out;                // scratch in d_out (k4 rewrites all)

  prep_kernel<<<512, 256, 0, stream>>>(w1, w2, wd, woff, ws);
  k1_fused_mfma<<<Bn * 196, 256, 0, stream>>>(x, w1b, b1, g1, be1, m1, v1, out1b);
  k2_offset_mfma<<<Bn * 49, 256, 0, stream>>>(out1b, wofb, boff, offs);
  k3_deform_mfma<<<Bn * 196, 256, 0, stream>>>(out1b, offs, wdb, bd,
                                               g2, be2, m2, v2, out2b);
  k4_mfma<<<Bn * 392, 256, 0, stream>>>(out2b, w2b, b2, g3, be3, m3, v3, x, out);
}